// Round 9
// baseline (270.115 us; speedup 1.0000x reference)
//
#include <hip/hip_runtime.h>
#include <hip/hip_bf16.h>
#include <math.h>

#define B_ 2
#define S_ 2048
#define E_ 2048
#define H_ 16
#define C_ 128

typedef __attribute__((ext_vector_type(8))) short s8v;   // 8 bf16 (4 VGPR) MFMA A/B frag
typedef __attribute__((ext_vector_type(4))) float f32x4; // MFMA C/D frag
typedef __attribute__((ext_vector_type(2))) unsigned u32x2;
typedef __attribute__((ext_vector_type(4))) unsigned u32x4;

#define MFMA16(a, b, c) __builtin_amdgcn_mfma_f32_16x16x32_bf16((a), (b), (c), 0, 0, 0)

__device__ __forceinline__ unsigned fbits(float f) {
    union { float f; unsigned u; } v{f};
    return v.u;
}
// half-up fp32->bf16 (2 VALU; |err| == RNE magnitude, ties round up)
__device__ __forceinline__ short f2bfh(float f) {
    return (short)((fbits(f) + 0x8000u) >> 16);
}
// pack two fp32 -> bf16x2 word (2 add + 1 v_perm); low short = lo, high = hi
__device__ __forceinline__ unsigned bfpack(float lo, float hi) {
    return __builtin_amdgcn_perm(fbits(hi) + 0x8000u, fbits(lo) + 0x8000u, 0x07060302u);
}

// raw HW exp2 (v_exp_f32): full-range (large-neg -> 0), ~1 ulp. Avoids the
// __ocml_exp2_f32 fixup sequence emitted without -ffast-math.
__device__ __forceinline__ float fexp2(float x) {
    float r;
    asm("v_exp_f32 %0, %1" : "=v"(r) : "v"(x));
    return r;
}
// raw HW reciprocal (epilogue only; ~1 ulp)
__device__ __forceinline__ float frcp(float x) {
    float r;
    asm("v_rcp_f32 %0, %1" : "=v"(r) : "v"(x));
    return r;
}

// async global->LDS, 16B/lane; LDS dest is wave-uniform base + lane*16
__device__ __forceinline__ void glds16(const void* g, void* l) {
    __builtin_amdgcn_global_load_lds(
        (const __attribute__((address_space(1))) void*)g,
        (__attribute__((address_space(3))) void*)l, 16, 0, 0);
}

// ---------------- Fused prep: K [b,s,h,c] -> Kb [b,h,s,c] bf16 (opt),
//                  V [b,s,h,c] -> Vt [b,h,c,s] bf16, and (blockIdx.y>=32)
//                  W fp32 -> bf16 — one launch instead of two. ----------------
template <bool DOK, bool DOW>
__global__ __launch_bounds__(256) void prep_all(
    const float* __restrict__ K, const float* __restrict__ V,
    const float* __restrict__ W,
    short* __restrict__ Kb, short* __restrict__ Vt, short* __restrict__ Wb)
{
    __shared__ __align__(16) short vt[C_][66];   // stride 132 B: write banks = c4, read <=2-way
    const int t = threadIdx.x;

    if (DOW && blockIdx.y >= 32) {
        // ---- convw part: 2048 logical blocks over W (e*e/8/256) ----
        int cid = (blockIdx.y - 32) * 32 + blockIdx.x;   // 0..2047
        size_t i = ((size_t)cid * 256 + t) * 8;
        float4 a = *(const float4*)(W + i);
        float4 b = *(const float4*)(W + i + 4);
        u32x4 o = {bfpack(a.x, a.y), bfpack(a.z, a.w), bfpack(b.x, b.y), bfpack(b.z, b.w)};
        *(u32x4*)(Wb + i) = o;
        return;
    }

    const int s0 = blockIdx.x * 64;
    const int bh = blockIdx.y;
    const int b = bh >> 4, h = bh & 15;

    if (DOK) {
#pragma unroll
        for (int i = 0; i < 8; ++i) {
            int idx = t + i * 256;
            int s = idx >> 5, c4 = idx & 31;
            float4 v = *(const float4*)(K + ((size_t)(b * S_ + s0 + s)) * E_ + h * C_ + c4 * 4);
            u32x2 o = {bfpack(v.x, v.y), bfpack(v.z, v.w)};
            *(u32x2*)(Kb + ((size_t)(bh * S_ + s0 + s)) * C_ + c4 * 4) = o;
        }
    }
    // V: row-coalesced loads (32 lanes cover one 512B row-slice), LDS transpose.
#pragma unroll
    for (int i = 0; i < 8; ++i) {
        int idx = t + i * 256;
        int r = idx >> 5, c4 = idx & 31;
        float4 v = *(const float4*)(V + ((size_t)(b * S_ + s0 + r)) * E_ + h * C_ + c4 * 4);
        vt[c4 * 4 + 0][r] = f2bfh(v.x);
        vt[c4 * 4 + 1][r] = f2bfh(v.y);
        vt[c4 * 4 + 2][r] = f2bfh(v.z);
        vt[c4 * 4 + 3][r] = f2bfh(v.w);
    }
    __syncthreads();
#pragma unroll
    for (int i = 0; i < 4; ++i) {
        int idx = t + i * 256;
        int c = idx >> 3, sc = idx & 7;
        *(s8v*)(Vt + ((size_t)(bh * C_ + c)) * S_ + s0 + sc * 8) = *(const s8v*)&vt[c][sc * 8];
    }
}

// ---------------- Flash attention (round-6/8 exact: 89.5us, FETCH 33MB) ----------------
// QT=256, 8 waves x 32 q-rows (2 m-tiles), dbuf ks/vs, 1 barrier/tile, XCD
// swizzle (xcd = head-group). Softmax p = exp2(s - M0), M0=16 fixed.
constexpr int QT = 256;
constexpr int KT = 64;
constexpr float M0 = 16.0f;

template <bool KBF16>
__global__ __launch_bounds__(512, 2) void attn_mfma(
    const short* __restrict__ Kb, const float* __restrict__ Kf,
    const float* __restrict__ Qp, const short* __restrict__ Vt,
    const int* __restrict__ maskp, short* __restrict__ Op)
{
    __shared__ __align__(16) short ks[2][KT * 128];  // 2 x 16 KB
    __shared__ __align__(16) short vs[2][C_ * 64];   // 2 x 16 KB
    __shared__ __align__(16) short ps[8][16][72];    // 18 KB wave-private P (per-mi reuse)

    const int t = threadIdx.x;
    const int w = t >> 6, lane = t & 63;             // w in 0..7
    const int c15 = lane & 15, quad = lane >> 4;
    // XCD-aware decode: xcd = id%8 picks the head-group, all 8 q-tiles of a
    // head land on the same XCD (bijective: id = xcd + 8*m + 32*qt).
    const int rbid = blockIdx.x;                     // 0..255
    const int hb = (rbid & 7) + 8 * ((rbid >> 3) & 3);
    const int q0 = (rbid >> 5) * QT;
    const int h = hb & 15, b = hb >> 4;
    const int bh = b * H_ + h;

    // Q fragments in registers (A-layout: m=c15, k=quad*8+j), scale = C^-0.5*log2(e)
    const float qscale = 0.12751744458187936f;
    s8v qf[2][4];
#pragma unroll
    for (int mi = 0; mi < 2; ++mi) {
        const float* qrow = Qp + ((size_t)(b * S_ + q0 + w * 32 + mi * 16 + c15)) * E_ + h * C_;
#pragma unroll
        for (int kk = 0; kk < 4; ++kk) {
            const float* p = qrow + kk * 32 + quad * 8;
            float4 x0 = *(const float4*)p;
            float4 x1 = *(const float4*)(p + 4);
            u32x4 pk = {bfpack(x0.x * qscale, x0.y * qscale),
                        bfpack(x0.z * qscale, x0.w * qscale),
                        bfpack(x1.x * qscale, x1.y * qscale),
                        bfpack(x1.z * qscale, x1.w * qscale)};
            qf[mi][kk] = *(s8v*)&pk;
        }
    }

    s8v ones;
#pragma unroll
    for (int j = 0; j < 8; ++j) ones[j] = (short)0x3F80;  // bf16 1.0

    f32x4 O[2][8], Ol[2];
#pragma unroll
    for (int mi = 0; mi < 2; ++mi) {
        Ol[mi] = (f32x4){0.f, 0.f, 0.f, 0.f};
#pragma unroll
        for (int ct = 0; ct < 8; ++ct) O[mi][ct] = (f32x4){0.f, 0.f, 0.f, 0.f};
    }

    const short* Kbh = Kb + (size_t)(bh * S_) * C_;
    const float* Kfh = Kf + (size_t)(b * S_) * E_ + h * C_;
    const short* Vbh = Vt + (size_t)(bh * C_) * S_;
    const int*   mptr = maskp + b * S_ + 4 * c15;   // per-lane 4 mask words

    // frag-read granule offsets (elements), swizzle folded in
    int kgp[4], vgp[2];
#pragma unroll
    for (int kk = 0; kk < 4; ++kk) kgp[kk] = ((4 * kk + quad) ^ c15) * 8;
#pragma unroll
    for (int ks2 = 0; ks2 < 2; ++ks2) vgp[ks2] = ((4 * ks2 + quad) ^ (c15 & 7)) * 8;

    // ---- stage K+V tile (bf16 path): 4 glds16/wave, pre-swizzled global src ----
    auto stage = [&](short* ksb, short* vsb, int k0) {
        const int r4 = lane >> 4, gp = lane & 15;
#pragma unroll
        for (int i = 0; i < 2; ++i) {
            int row = w * 8 + i * 4 + r4;
            int g = gp ^ ((row >> 2) & 15);
            glds16(Kbh + (size_t)(k0 + row) * C_ + g * 8, ksb + (w * 8 + i * 4) * 128);
        }
        const int cr = lane >> 3, gp7 = lane & 7;
#pragma unroll
        for (int i = 0; i < 2; ++i) {
            int c = w * 16 + i * 8 + cr;
            int g = gp7 ^ (c & 7);
            glds16(Vbh + (size_t)c * S_ + k0 + g * 8, vsb + (w * 16 + i * 8) * 64);
        }
    };

    // ---- QK -> softmax -> PV for one K-tile (M=32 per wave) ----
    auto compute = [&](const short* ksc, const short* vsc, int4 mv) {
        float bva[4] = {mv.x ? -M0 : -1e30f, mv.y ? -M0 : -1e30f,
                        mv.z ? -M0 : -1e30f, mv.w ? -M0 : -1e30f};
        f32x4 Sf[2][4];
        __builtin_amdgcn_s_setprio(1);
#pragma unroll
        for (int nt = 0; nt < 4; ++nt) {
            f32x4 s0 = (f32x4){bva[nt], bva[nt], bva[nt], bva[nt]};
            f32x4 s1 = s0;
            const short* krow = ksc + (4 * c15 + nt) * 128;
#pragma unroll
            for (int kk = 0; kk < 4; ++kk) {
                s8v bf = *(const s8v*)(krow + kgp[kk]);
                s0 = MFMA16(qf[0][kk], bf, s0);
                s1 = MFMA16(qf[1][kk], bf, s1);
            }
            Sf[0][nt] = s0; Sf[1][nt] = s1;
        }
        __builtin_amdgcn_s_setprio(0);

        // P = exp2(S) -> wave-private LDS, one mi at a time (same-wave in-order
        // DS makes write(mi0)->read(af0)->write(mi1)->read(af1) on same rows safe)
        s8v af[2][2];
#pragma unroll
        for (int mi = 0; mi < 2; ++mi) {
#pragma unroll
            for (int r = 0; r < 4; ++r) {
                float p0 = fexp2(Sf[mi][0][r]);
                float p1 = fexp2(Sf[mi][1][r]);
                float p2 = fexp2(Sf[mi][2][r]);
                float p3 = fexp2(Sf[mi][3][r]);
                u32x2 d = {bfpack(p0, p1), bfpack(p2, p3)};
                *(u32x2*)&ps[w][quad * 4 + r][4 * c15] = d;
            }
#pragma unroll
            for (int ks2 = 0; ks2 < 2; ++ks2)
                af[mi][ks2] = *(const s8v*)&ps[w][c15][ks2 * 32 + quad * 8];
        }

        // O += P V ;  l += P 1   (V-frag reads amortized over both m-tiles)
        __builtin_amdgcn_s_setprio(1);
#pragma unroll
        for (int ct = 0; ct < 8; ++ct) {
            const short* vrow = vsc + (ct * 16 + c15) * 64;
#pragma unroll
            for (int ks2 = 0; ks2 < 2; ++ks2) {
                s8v bf = *(const s8v*)(vrow + vgp[ks2]);
                O[0][ct] = MFMA16(af[0][ks2], bf, O[0][ct]);
                O[1][ct] = MFMA16(af[1][ks2], bf, O[1][ct]);
            }
        }
#pragma unroll
        for (int mi = 0; mi < 2; ++mi) {
            Ol[mi] = MFMA16(af[mi][0], ones, Ol[mi]);
            Ol[mi] = MFMA16(af[mi][1], ones, Ol[mi]);
        }
        __builtin_amdgcn_s_setprio(0);
    };

    if (KBF16) {
        // -------- dbuf: prefetch tile k+1 at top, ONE barrier per tile --------
        stage(&ks[0][0], &vs[0][0], 0);
        int4 mcur = *(const int4*)mptr;
        __syncthreads();                       // vmcnt(0) drain lands tile 0
#pragma unroll 1
        for (int k0 = 0; k0 < S_; k0 += 2 * KT) {
            stage(&ks[1][0], &vs[1][0], k0 + KT);        // always valid (<= 1984)
            int4 m1 = *(const int4*)(mptr + k0 + KT);
            compute(&ks[0][0], &vs[0][0], mcur);
            __syncthreads();                   // drains prefetch of tile k0+KT

            int4 m2 = m1;
            if (k0 + 2 * KT < S_) {
                stage(&ks[0][0], &vs[0][0], k0 + 2 * KT);
                m2 = *(const int4*)(mptr + k0 + 2 * KT);
            }
            compute(&ks[1][0], &vs[1][0], m1);
            mcur = m2;
            __syncthreads();
        }
    } else {
        // -------- fallback (fp32 K): single-buffer, two barriers --------
#pragma unroll 1
        for (int k0 = 0; k0 < S_; k0 += KT) {
#pragma unroll
            for (int i = 0; i < 4; ++i) {
                int idx = t + i * 512;
                int r = idx >> 5, c4 = idx & 31;
                float4 kv = *(const float4*)(Kfh + (size_t)(k0 + r) * E_ + c4 * 4);
                u32x2 sv = {bfpack(kv.x, kv.y), bfpack(kv.z, kv.w)};
                int gpw = (c4 >> 1) ^ ((r >> 2) & 15);
                *(u32x2*)&ks[0][r * 128 + gpw * 8 + (c4 & 1) * 4] = sv;
            }
            {
                const int cr = lane >> 3, gp7 = lane & 7;
#pragma unroll
                for (int i = 0; i < 2; ++i) {
                    int c = w * 16 + i * 8 + cr;
                    int g = gp7 ^ (c & 7);
                    glds16(Vbh + (size_t)c * S_ + k0 + g * 8, &vs[0][(w * 16 + i * 8) * 64]);
                }
            }
            int4 mv = *(const int4*)(mptr + k0);
            __syncthreads();
            compute(&ks[0][0], &vs[0][0], mv);
            __syncthreads();
        }
    }

    // ---- epilogue: normalize by l (same D-layout rows), write bf16 ----
#pragma unroll
    for (int mi = 0; mi < 2; ++mi) {
        float inv[4];
#pragma unroll
        for (int r = 0; r < 4; ++r) inv[r] = frcp(Ol[mi][r]);
        size_t rbase = (size_t)(b * S_ + q0 + w * 32 + mi * 16 + quad * 4) * E_ + h * C_;
#pragma unroll
        for (int ct = 0; ct < 8; ++ct)
#pragma unroll
            for (int r = 0; r < 4; ++r)
                Op[rbase + (size_t)r * E_ + ct * 16 + c15] = f2bfh(O[mi][ct][r] * inv[r]);
    }
}

// ---------------- Projection: Y[4096,2048] = X_bf16 @ W^T ----------------
// THIS ROUND: wave tile 64x64 (acc[4][4] = 64 VGPR, counted — no r7 spill
// repeat; ~120 total vs 256 cap) in the ROUND-2 shell that measured best:
// 256 thr / 4 waves, block tile 128x128, dbuf As/Bs = 64 KB -> 2 blocks/CU
// (cross-block barrier cover), prefetch at top, one __syncthreads per K-step.
// 16 ds_read_b128 per 32 MFMA (was 12 per 16): -33% total LDS reads.
// XCD decode kept: xcd = bn-panel & 7 -> W-panels L2-resident.
template <bool WBF16>
__global__ __launch_bounds__(256, 2) void proj_mfma(
    const short* __restrict__ X, const short* __restrict__ Wb,
    const float* __restrict__ Wf, float* __restrict__ Y)
{
    __shared__ __align__(16) short As[2][128 * 64];  // 2 x 16 KB
    __shared__ __align__(16) short Bs[2][128 * 64];  // 2 x 16 KB

    const int t = threadIdx.x;
    const int w = t >> 6, lane = t & 63;             // w in 0..3
    const int c15 = lane & 15, quad = lane >> 4;
    // XCD-aware decode: bijective over 512 blocks; xcd = id%8 = bn-panel & 7.
    const int pid = blockIdx.x;                      // 0..511
    const int bn = ((pid & 7) + 8 * ((pid >> 3) & 1)) * 128;  // 16 n-panels
    const int bm = (pid >> 4) * 128;                          // 32 m-panels
    const int wm = (w >> 1) * 64, wn = (w & 1) * 64;

    f32x4 acc[4][4];
#pragma unroll
    for (int mi = 0; mi < 4; ++mi)
#pragma unroll
        for (int ni = 0; ni < 4; ++ni) acc[mi][ni] = (f32x4){0.f, 0.f, 0.f, 0.f};

    int agp[2];
#pragma unroll
    for (int kk = 0; kk < 2; ++kk) agp[kk] = ((4 * kk + quad) ^ (c15 & 7)) * 8;

    auto stageAB = [&](short* Ab, short* Bb, int k0) {
        const int r8 = lane >> 3, gp = lane & 7;
#pragma unroll
        for (int i = 0; i < 4; ++i) {
            int row = w * 32 + i * 8 + r8;
            int g = gp ^ (row & 7);
            glds16(X + (size_t)(bm + row) * E_ + k0 + g * 8, Ab + (w * 32 + i * 8) * 64);
            glds16(Wb + (size_t)(bn + row) * E_ + k0 + g * 8, Bb + (w * 32 + i * 8) * 64);
        }
    };

    auto compute = [&](const short* Ab, const short* Bb) {
#pragma unroll
        for (int kk = 0; kk < 2; ++kk) {
            s8v a[4], bb[4];
#pragma unroll
            for (int mi = 0; mi < 4; ++mi)
                a[mi] = *(const s8v*)(Ab + (wm + mi * 16 + c15) * 64 + agp[kk]);
#pragma unroll
            for (int ni = 0; ni < 4; ++ni)
                bb[ni] = *(const s8v*)(Bb + (wn + ni * 16 + c15) * 64 + agp[kk]);
#pragma unroll
            for (int mi = 0; mi < 4; ++mi)
#pragma unroll
                for (int ni = 0; ni < 4; ++ni)
                    acc[mi][ni] = MFMA16(a[mi], bb[ni], acc[mi][ni]);
        }
    };

    if (WBF16) {
        stageAB(&As[0][0], &Bs[0][0], 0);
        __syncthreads();
#pragma unroll 1
        for (int k0 = 0; k0 < E_; k0 += 128) {
            stageAB(&As[1][0], &Bs[1][0], k0 + 64);      // always valid (<= 1984)
            compute(&As[0][0], &Bs[0][0]);
            __syncthreads();

            if (k0 + 128 < E_) stageAB(&As[0][0], &Bs[0][0], k0 + 128);
            compute(&As[1][0], &Bs[1][0]);
            __syncthreads();
        }
    } else {
        // fallback (fp32 W): single-buffer, two barriers
#pragma unroll 1
        for (int k0 = 0; k0 < E_; k0 += 64) {
            {
                const int r8 = lane >> 3, gp = lane & 7;
#pragma unroll
                for (int i = 0; i < 4; ++i) {
                    int row = w * 32 + i * 8 + r8;
                    int g = gp ^ (row & 7);
                    glds16(X + (size_t)(bm + row) * E_ + k0 + g * 8, &As[0][(w * 32 + i * 8) * 64]);
                }
            }
#pragma unroll
            for (int i = 0; i < 8; ++i) {
                int idx = t + i * 256;
                int r = idx >> 4, c4 = idx & 15;
                float4 wv = *(const float4*)(Wf + (size_t)(bn + r) * E_ + k0 + c4 * 4);
                u32x2 sv = {bfpack(wv.x, wv.y), bfpack(wv.z, wv.w)};
                int gpw = (c4 >> 1) ^ (r & 7);
                *(u32x2*)&Bs[0][r * 64 + gpw * 8 + (c4 & 1) * 4] = sv;
            }
            __syncthreads();
            compute(&As[0][0], &Bs[0][0]);
            __syncthreads();
        }
    }

#pragma unroll
    for (int mi = 0; mi < 4; ++mi)
#pragma unroll
        for (int ni = 0; ni < 4; ++ni) {
            size_t rbase = (size_t)(bm + wm + mi * 16 + quad * 4) * E_ + bn + wn + ni * 16 + c15;
#pragma unroll
            for (int r = 0; r < 4; ++r) Y[rbase + (size_t)r * E_] = acc[mi][ni][r];
        }
}

extern "C" void kernel_launch(void* const* d_in, const int* in_sizes, int n_in,
                              void* d_out, int out_size, void* d_ws, size_t ws_size,
                              hipStream_t stream) {
    const float* keys    = (const float*)d_in[0];
    const float* values  = (const float*)d_in[1];
    const float* queries = (const float*)d_in[2];
    const int*   mask    = (const int*)d_in[3];
    const float* w_out   = (const float*)d_in[4];
    float* out = (float*)d_out;

    const size_t EL = (size_t)B_ * S_ * E_;   // 8388608 elements per tensor
    short* ws  = (short*)d_ws;
    short* VtW = ws;            // [b,h,c,s] bf16   (16.78 MB)
    short* Xb  = ws + EL;       // attn out [b,s,e] (16.78 MB)
    short* Kb  = ws + 2 * EL;   // [b,h,s,c] bf16   (16.78 MB)
    short* Wb  = ws + 3 * EL;   // [e,e] bf16       ( 8.39 MB)

    const bool hasK = ws_size >= (3 * EL) * 2;                       // 50.3 MB
    const bool hasW = ws_size >= (3 * EL + (size_t)E_ * E_) * 2;     // 58.7 MB

    // merged prep: y<32 = K/V prep, y>=32 = W conversion (one launch, one gap)
    if (hasK && hasW)
        prep_all<true, true><<<dim3(S_ / 64, 96), 256, 0, stream>>>(keys, values, w_out, Kb, VtW, Wb);
    else if (hasK)
        prep_all<true, false><<<dim3(S_ / 64, 32), 256, 0, stream>>>(keys, values, w_out, Kb, VtW, Wb);
    else
        prep_all<false, false><<<dim3(S_ / 64, 32), 256, 0, stream>>>(keys, values, w_out, Kb, VtW, Wb);

    // 1-D grid, XCD-aware decode inside the kernel (256 blocks)
    if (hasK)
        attn_mfma<true><<<dim3((S_ / QT) * H_ * B_), 512, 0, stream>>>(Kb, keys, queries, VtW, mask, Xb);
    else
        attn_mfma<false><<<dim3((S_ / QT) * H_ * B_), 512, 0, stream>>>(Kb, keys, queries, VtW, mask, Xb);

    // 1-D grid (512 blocks), XCD-aware decode inside the kernel
    if (hasW)
        proj_mfma<true><<<dim3(512), 256, 0, stream>>>(Xb, Wb, w_out, out);
    else
        proj_mfma<false><<<dim3(512), 256, 0, stream>>>(Xb, Wb, w_out, out);
}

// Round 10
// 263.300 us; speedup vs baseline: 1.0259x; 1.0259x over previous
//
#include <hip/hip_runtime.h>
#include <hip/hip_bf16.h>
#include <math.h>

#define B_ 2
#define S_ 2048
#define E_ 2048
#define H_ 16
#define C_ 128

typedef __attribute__((ext_vector_type(8))) short s8v;   // 8 bf16 (4 VGPR) MFMA A/B frag
typedef __attribute__((ext_vector_type(4))) float f32x4; // MFMA C/D frag
typedef __attribute__((ext_vector_type(2))) unsigned u32x2;
typedef __attribute__((ext_vector_type(4))) unsigned u32x4;

#define MFMA16(a, b, c) __builtin_amdgcn_mfma_f32_16x16x32_bf16((a), (b), (c), 0, 0, 0)

__device__ __forceinline__ unsigned fbits(float f) {
    union { float f; unsigned u; } v{f};
    return v.u;
}
// half-up fp32->bf16 (2 VALU; |err| == RNE magnitude, ties round up)
__device__ __forceinline__ short f2bfh(float f) {
    return (short)((fbits(f) + 0x8000u) >> 16);
}
// pack two fp32 -> bf16x2 word (2 add + 1 v_perm); low short = lo, high = hi
__device__ __forceinline__ unsigned bfpack(float lo, float hi) {
    return __builtin_amdgcn_perm(fbits(hi) + 0x8000u, fbits(lo) + 0x8000u, 0x07060302u);
}

// raw HW exp2 (v_exp_f32): full-range (large-neg -> 0), ~1 ulp. Avoids the
// __ocml_exp2_f32 fixup sequence emitted without -ffast-math.
__device__ __forceinline__ float fexp2(float x) {
    float r;
    asm("v_exp_f32 %0, %1" : "=v"(r) : "v"(x));
    return r;
}
// raw HW reciprocal (epilogue only; ~1 ulp)
__device__ __forceinline__ float frcp(float x) {
    float r;
    asm("v_rcp_f32 %0, %1" : "=v"(r) : "v"(x));
    return r;
}

// async global->LDS, 16B/lane; LDS dest is wave-uniform base + lane*16
__device__ __forceinline__ void glds16(const void* g, void* l) {
    __builtin_amdgcn_global_load_lds(
        (const __attribute__((address_space(1))) void*)g,
        (__attribute__((address_space(3))) void*)l, 16, 0, 0);
}

// ---------------- Fused prep: K [b,s,h,c] -> Kb [b,h,s,c] bf16 (opt)
//                  and V [b,s,h,c] -> Vt [b,h,c,s] bf16 ----------------
template <bool DOK>
__global__ __launch_bounds__(256) void prep_kv(
    const float* __restrict__ K, const float* __restrict__ V,
    short* __restrict__ Kb, short* __restrict__ Vt)
{
    __shared__ __align__(16) short vt[C_][66];   // stride 132 B: write banks = c4, read <=2-way
    const int t  = threadIdx.x;
    const int s0 = blockIdx.x * 64;
    const int bh = blockIdx.y;
    const int b = bh >> 4, h = bh & 15;

    if (DOK) {
#pragma unroll
        for (int i = 0; i < 8; ++i) {
            int idx = t + i * 256;
            int s = idx >> 5, c4 = idx & 31;
            float4 v = *(const float4*)(K + ((size_t)(b * S_ + s0 + s)) * E_ + h * C_ + c4 * 4);
            u32x2 o = {bfpack(v.x, v.y), bfpack(v.z, v.w)};
            *(u32x2*)(Kb + ((size_t)(bh * S_ + s0 + s)) * C_ + c4 * 4) = o;
        }
    }
    // V: row-coalesced loads (32 lanes cover one 512B row-slice), LDS transpose.
#pragma unroll
    for (int i = 0; i < 8; ++i) {
        int idx = t + i * 256;
        int r = idx >> 5, c4 = idx & 31;
        float4 v = *(const float4*)(V + ((size_t)(b * S_ + s0 + r)) * E_ + h * C_ + c4 * 4);
        vt[c4 * 4 + 0][r] = f2bfh(v.x);
        vt[c4 * 4 + 1][r] = f2bfh(v.y);
        vt[c4 * 4 + 2][r] = f2bfh(v.z);
        vt[c4 * 4 + 3][r] = f2bfh(v.w);
    }
    __syncthreads();
#pragma unroll
    for (int i = 0; i < 4; ++i) {
        int idx = t + i * 256;
        int c = idx >> 3, sc = idx & 7;
        *(s8v*)(Vt + ((size_t)(bh * C_ + c)) * S_ + s0 + sc * 8) = *(const s8v*)&vt[c][sc * 8];
    }
}

// ---------------- Prep: W fp32 -> bf16 ----------------
__global__ __launch_bounds__(256) void convw_kernel(
    const float* __restrict__ W, short* __restrict__ Wb)
{
    size_t i = ((size_t)blockIdx.x * 256 + threadIdx.x) * 8;
    float4 a = *(const float4*)(W + i);
    float4 b = *(const float4*)(W + i + 4);
    u32x4 o = {bfpack(a.x, a.y), bfpack(a.z, a.w), bfpack(b.x, b.y), bfpack(b.z, b.w)};
    *(u32x4*)(Wb + i) = o;
}

// ---------------- Flash attention (measured 89.5us, FETCH 33MB) ----------------
// QT=256, 8 waves x 32 q-rows (2 m-tiles), dbuf ks/vs, 1 barrier/tile, XCD
// swizzle (xcd = head-group). Softmax p = exp2(s - M0), M0=16 fixed.
constexpr int QT = 256;
constexpr int KT = 64;
constexpr float M0 = 16.0f;

template <bool KBF16>
__global__ __launch_bounds__(512, 2) void attn_mfma(
    const short* __restrict__ Kb, const float* __restrict__ Kf,
    const float* __restrict__ Qp, const short* __restrict__ Vt,
    const int* __restrict__ maskp, short* __restrict__ Op)
{
    __shared__ __align__(16) short ks[2][KT * 128];  // 2 x 16 KB
    __shared__ __align__(16) short vs[2][C_ * 64];   // 2 x 16 KB
    __shared__ __align__(16) short ps[8][16][72];    // 18 KB wave-private P (per-mi reuse)

    const int t = threadIdx.x;
    const int w = t >> 6, lane = t & 63;             // w in 0..7
    const int c15 = lane & 15, quad = lane >> 4;
    // XCD-aware decode: xcd = id%8 picks the head-group, all 8 q-tiles of a
    // head land on the same XCD (bijective: id = xcd + 8*m + 32*qt).
    const int rbid = blockIdx.x;                     // 0..255
    const int hb = (rbid & 7) + 8 * ((rbid >> 3) & 3);
    const int q0 = (rbid >> 5) * QT;
    const int h = hb & 15, b = hb >> 4;
    const int bh = b * H_ + h;

    // Q fragments in registers (A-layout: m=c15, k=quad*8+j), scale = C^-0.5*log2(e)
    const float qscale = 0.12751744458187936f;
    s8v qf[2][4];
#pragma unroll
    for (int mi = 0; mi < 2; ++mi) {
        const float* qrow = Qp + ((size_t)(b * S_ + q0 + w * 32 + mi * 16 + c15)) * E_ + h * C_;
#pragma unroll
        for (int kk = 0; kk < 4; ++kk) {
            const float* p = qrow + kk * 32 + quad * 8;
            float4 x0 = *(const float4*)p;
            float4 x1 = *(const float4*)(p + 4);
            u32x4 pk = {bfpack(x0.x * qscale, x0.y * qscale),
                        bfpack(x0.z * qscale, x0.w * qscale),
                        bfpack(x1.x * qscale, x1.y * qscale),
                        bfpack(x1.z * qscale, x1.w * qscale)};
            qf[mi][kk] = *(s8v*)&pk;
        }
    }

    s8v ones;
#pragma unroll
    for (int j = 0; j < 8; ++j) ones[j] = (short)0x3F80;  // bf16 1.0

    f32x4 O[2][8], Ol[2];
#pragma unroll
    for (int mi = 0; mi < 2; ++mi) {
        Ol[mi] = (f32x4){0.f, 0.f, 0.f, 0.f};
#pragma unroll
        for (int ct = 0; ct < 8; ++ct) O[mi][ct] = (f32x4){0.f, 0.f, 0.f, 0.f};
    }

    const short* Kbh = Kb + (size_t)(bh * S_) * C_;
    const float* Kfh = Kf + (size_t)(b * S_) * E_ + h * C_;
    const short* Vbh = Vt + (size_t)(bh * C_) * S_;
    const int*   mptr = maskp + b * S_ + 4 * c15;   // per-lane 4 mask words

    // frag-read granule offsets (elements), swizzle folded in
    int kgp[4], vgp[2];
#pragma unroll
    for (int kk = 0; kk < 4; ++kk) kgp[kk] = ((4 * kk + quad) ^ c15) * 8;
#pragma unroll
    for (int ks2 = 0; ks2 < 2; ++ks2) vgp[ks2] = ((4 * ks2 + quad) ^ (c15 & 7)) * 8;

    // ---- stage K+V tile (bf16 path): 4 glds16/wave, pre-swizzled global src ----
    auto stage = [&](short* ksb, short* vsb, int k0) {
        const int r4 = lane >> 4, gp = lane & 15;
#pragma unroll
        for (int i = 0; i < 2; ++i) {
            int row = w * 8 + i * 4 + r4;
            int g = gp ^ ((row >> 2) & 15);
            glds16(Kbh + (size_t)(k0 + row) * C_ + g * 8, ksb + (w * 8 + i * 4) * 128);
        }
        const int cr = lane >> 3, gp7 = lane & 7;
#pragma unroll
        for (int i = 0; i < 2; ++i) {
            int c = w * 16 + i * 8 + cr;
            int g = gp7 ^ (c & 7);
            glds16(Vbh + (size_t)c * S_ + k0 + g * 8, vsb + (w * 16 + i * 8) * 64);
        }
    };

    // ---- QK -> softmax -> PV for one K-tile (M=32 per wave) ----
    auto compute = [&](const short* ksc, const short* vsc, int4 mv) {
        float bva[4] = {mv.x ? -M0 : -1e30f, mv.y ? -M0 : -1e30f,
                        mv.z ? -M0 : -1e30f, mv.w ? -M0 : -1e30f};
        f32x4 Sf[2][4];
        __builtin_amdgcn_s_setprio(1);
#pragma unroll
        for (int nt = 0; nt < 4; ++nt) {
            f32x4 s0 = (f32x4){bva[nt], bva[nt], bva[nt], bva[nt]};
            f32x4 s1 = s0;
            const short* krow = ksc + (4 * c15 + nt) * 128;
#pragma unroll
            for (int kk = 0; kk < 4; ++kk) {
                s8v bf = *(const s8v*)(krow + kgp[kk]);
                s0 = MFMA16(qf[0][kk], bf, s0);
                s1 = MFMA16(qf[1][kk], bf, s1);
            }
            Sf[0][nt] = s0; Sf[1][nt] = s1;
        }
        __builtin_amdgcn_s_setprio(0);

        // P = exp2(S) -> wave-private LDS, one mi at a time (same-wave in-order
        // DS makes write(mi0)->read(af0)->write(mi1)->read(af1) on same rows safe)
        s8v af[2][2];
#pragma unroll
        for (int mi = 0; mi < 2; ++mi) {
#pragma unroll
            for (int r = 0; r < 4; ++r) {
                float p0 = fexp2(Sf[mi][0][r]);
                float p1 = fexp2(Sf[mi][1][r]);
                float p2 = fexp2(Sf[mi][2][r]);
                float p3 = fexp2(Sf[mi][3][r]);
                u32x2 d = {bfpack(p0, p1), bfpack(p2, p3)};
                *(u32x2*)&ps[w][quad * 4 + r][4 * c15] = d;
            }
#pragma unroll
            for (int ks2 = 0; ks2 < 2; ++ks2)
                af[mi][ks2] = *(const s8v*)&ps[w][c15][ks2 * 32 + quad * 8];
        }

        // O += P V ;  l += P 1   (V-frag reads amortized over both m-tiles)
        __builtin_amdgcn_s_setprio(1);
#pragma unroll
        for (int ct = 0; ct < 8; ++ct) {
            const short* vrow = vsc + (ct * 16 + c15) * 64;
#pragma unroll
            for (int ks2 = 0; ks2 < 2; ++ks2) {
                s8v bf = *(const s8v*)(vrow + vgp[ks2]);
                O[0][ct] = MFMA16(af[0][ks2], bf, O[0][ct]);
                O[1][ct] = MFMA16(af[1][ks2], bf, O[1][ct]);
            }
        }
#pragma unroll
        for (int mi = 0; mi < 2; ++mi) {
            Ol[mi] = MFMA16(af[mi][0], ones, Ol[mi]);
            Ol[mi] = MFMA16(af[mi][1], ones, Ol[mi]);
        }
        __builtin_amdgcn_s_setprio(0);
    };

    if (KBF16) {
        // -------- dbuf: prefetch tile k+1 at top, ONE barrier per tile --------
        stage(&ks[0][0], &vs[0][0], 0);
        int4 mcur = *(const int4*)mptr;
        __syncthreads();                       // vmcnt(0) drain lands tile 0
#pragma unroll 1
        for (int k0 = 0; k0 < S_; k0 += 2 * KT) {
            stage(&ks[1][0], &vs[1][0], k0 + KT);        // always valid (<= 1984)
            int4 m1 = *(const int4*)(mptr + k0 + KT);
            compute(&ks[0][0], &vs[0][0], mcur);
            __syncthreads();                   // drains prefetch of tile k0+KT

            int4 m2 = m1;
            if (k0 + 2 * KT < S_) {
                stage(&ks[0][0], &vs[0][0], k0 + 2 * KT);
                m2 = *(const int4*)(mptr + k0 + 2 * KT);
            }
            compute(&ks[1][0], &vs[1][0], m1);
            mcur = m2;
            __syncthreads();
        }
    } else {
        // -------- fallback (fp32 K): single-buffer, two barriers --------
#pragma unroll 1
        for (int k0 = 0; k0 < S_; k0 += KT) {
#pragma unroll
            for (int i = 0; i < 4; ++i) {
                int idx = t + i * 512;
                int r = idx >> 5, c4 = idx & 31;
                float4 kv = *(const float4*)(Kfh + (size_t)(k0 + r) * E_ + c4 * 4);
                u32x2 sv = {bfpack(kv.x, kv.y), bfpack(kv.z, kv.w)};
                int gpw = (c4 >> 1) ^ ((r >> 2) & 15);
                *(u32x2*)&ks[0][r * 128 + gpw * 8 + (c4 & 1) * 4] = sv;
            }
            {
                const int cr = lane >> 3, gp7 = lane & 7;
#pragma unroll
                for (int i = 0; i < 2; ++i) {
                    int c = w * 16 + i * 8 + cr;
                    int g = gp7 ^ (c & 7);
                    glds16(Vbh + (size_t)c * S_ + k0 + g * 8, &vs[0][(w * 16 + i * 8) * 64]);
                }
            }
            int4 mv = *(const int4*)(mptr + k0);
            __syncthreads();
            compute(&ks[0][0], &vs[0][0], mv);
            __syncthreads();
        }
    }

    // ---- epilogue: normalize by l (same D-layout rows), write bf16 ----
#pragma unroll
    for (int mi = 0; mi < 2; ++mi) {
        float inv[4];
#pragma unroll
        for (int r = 0; r < 4; ++r) inv[r] = frcp(Ol[mi][r]);
        size_t rbase = (size_t)(b * S_ + q0 + w * 32 + mi * 16 + quad * 4) * E_ + h * C_;
#pragma unroll
        for (int ct = 0; ct < 8; ++ct)
#pragma unroll
            for (int r = 0; r < 4; ++r)
                Op[rbase + (size_t)r * E_ + ct * 16 + c15] = f2bfh(O[mi][ct][r] * inv[r]);
    }
}

// ---------------- Projection: Y[4096,2048] = X_bf16 @ W^T ----------------
// Round-8 exact (measured best): 512 thr / 8 waves, wave tile 64x32 (acc[4][2],
// VGPR 64), block tile 128x128, dbuf As/Bs (64 KB -> 2 blocks/CU), prefetch at
// top, one __syncthreads per K-step. XCD decode: xcd = bn-panel & 7 -> each
// XCD serves 2 W-panels (1 MB, L2-resident).
template <bool WBF16>
__global__ __launch_bounds__(512, 2) void proj_mfma(
    const short* __restrict__ X, const short* __restrict__ Wb,
    const float* __restrict__ Wf, float* __restrict__ Y)
{
    __shared__ __align__(16) short As[2][128 * 64];  // 2 x 16 KB
    __shared__ __align__(16) short Bs[2][128 * 64];  // 2 x 16 KB

    const int t = threadIdx.x;
    const int w = t >> 6, lane = t & 63;             // w in 0..7
    const int c15 = lane & 15, quad = lane >> 4;
    // XCD-aware decode: bijective over 512 blocks; xcd = id%8 = bn-panel & 7.
    const int pid = blockIdx.x;                      // 0..511
    const int bn = ((pid & 7) + 8 * ((pid >> 3) & 1)) * 128;  // 16 n-panels
    const int bm = (pid >> 4) * 128;                          // 32 m-panels
    const int wm = (w >> 2) * 64, wn = (w & 3) * 32;

    f32x4 acc[4][2];
#pragma unroll
    for (int mi = 0; mi < 4; ++mi)
#pragma unroll
        for (int ni = 0; ni < 2; ++ni) acc[mi][ni] = (f32x4){0.f, 0.f, 0.f, 0.f};

    int agp[2];
#pragma unroll
    for (int kk = 0; kk < 2; ++kk) agp[kk] = ((4 * kk + quad) ^ (c15 & 7)) * 8;

    auto stageAB = [&](short* Ab, short* Bb, int k0) {
        const int r8 = lane >> 3, gp = lane & 7;
#pragma unroll
        for (int i = 0; i < 2; ++i) {
            int row = w * 16 + i * 8 + r8;
            int g = gp ^ (row & 7);
            glds16(X + (size_t)(bm + row) * E_ + k0 + g * 8, Ab + (w * 16 + i * 8) * 64);
            glds16(Wb + (size_t)(bn + row) * E_ + k0 + g * 8, Bb + (w * 16 + i * 8) * 64);
        }
    };

    auto compute = [&](const short* Ab, const short* Bb) {
#pragma unroll
        for (int kk = 0; kk < 2; ++kk) {
            s8v a[4], bb[2];
#pragma unroll
            for (int mi = 0; mi < 4; ++mi)
                a[mi] = *(const s8v*)(Ab + (wm + mi * 16 + c15) * 64 + agp[kk]);
#pragma unroll
            for (int ni = 0; ni < 2; ++ni)
                bb[ni] = *(const s8v*)(Bb + (wn + ni * 16 + c15) * 64 + agp[kk]);
#pragma unroll
            for (int mi = 0; mi < 4; ++mi)
#pragma unroll
                for (int ni = 0; ni < 2; ++ni)
                    acc[mi][ni] = MFMA16(a[mi], bb[ni], acc[mi][ni]);
        }
    };

    if (WBF16) {
        stageAB(&As[0][0], &Bs[0][0], 0);
        __syncthreads();
#pragma unroll 1
        for (int k0 = 0; k0 < E_; k0 += 128) {
            stageAB(&As[1][0], &Bs[1][0], k0 + 64);      // always valid (<= 1984)
            compute(&As[0][0], &Bs[0][0]);
            __syncthreads();

            if (k0 + 128 < E_) stageAB(&As[0][0], &Bs[0][0], k0 + 128);
            compute(&As[1][0], &Bs[1][0]);
            __syncthreads();
        }
    } else {
        // fallback (fp32 W): single-buffer, two barriers
#pragma unroll 1
        for (int k0 = 0; k0 < E_; k0 += 64) {
            {
                const int r8 = lane >> 3, gp = lane & 7;
#pragma unroll
                for (int i = 0; i < 2; ++i) {
                    int row = w * 16 + i * 8 + r8;
                    int g = gp ^ (row & 7);
                    glds16(X + (size_t)(bm + row) * E_ + k0 + g * 8, &As[0][(w * 16 + i * 8) * 64]);
                }
            }
#pragma unroll
            for (int i = 0; i < 4; ++i) {
                int idx = t + i * 512;
                int r = idx >> 4, c4 = idx & 15;
                float4 wv = *(const float4*)(Wf + (size_t)(bn + r) * E_ + k0 + c4 * 4);
                u32x2 sv = {bfpack(wv.x, wv.y), bfpack(wv.z, wv.w)};
                int gpw = (c4 >> 1) ^ (r & 7);
                *(u32x2*)&Bs[0][r * 64 + gpw * 8 + (c4 & 1) * 4] = sv;
            }
            __syncthreads();
            compute(&As[0][0], &Bs[0][0]);
            __syncthreads();
        }
    }

#pragma unroll
    for (int mi = 0; mi < 4; ++mi)
#pragma unroll
        for (int ni = 0; ni < 2; ++ni) {
            size_t rbase = (size_t)(bm + wm + mi * 16 + quad * 4) * E_ + bn + wn + ni * 16 + c15;
#pragma unroll
            for (int r = 0; r < 4; ++r) Y[rbase + (size_t)r * E_] = acc[mi][ni][r];
        }
}

extern "C" void kernel_launch(void* const* d_in, const int* in_sizes, int n_in,
                              void* d_out, int out_size, void* d_ws, size_t ws_size,
                              hipStream_t stream) {
    const float* keys    = (const float*)d_in[0];
    const float* values  = (const float*)d_in[1];
    const float* queries = (const float*)d_in[2];
    const int*   mask    = (const int*)d_in[3];
    const float* w_out   = (const float*)d_in[4];
    float* out = (float*)d_out;

    const size_t EL = (size_t)B_ * S_ * E_;   // 8388608 elements per tensor
    short* ws  = (short*)d_ws;
    short* VtW = ws;            // [b,h,c,s] bf16   (16.78 MB)
    short* Xb  = ws + EL;       // attn out [b,s,e] (16.78 MB)
    short* Kb  = ws + 2 * EL;   // [b,h,s,c] bf16   (16.78 MB)
    short* Wb  = ws + 3 * EL;   // [e,e] bf16       ( 8.39 MB)

    const bool hasK = ws_size >= (3 * EL) * 2;                       // 50.3 MB
    const bool hasW = ws_size >= (3 * EL + (size_t)E_ * E_) * 2;     // 58.7 MB

    if (hasK)
        prep_kv<true><<<dim3(S_ / 64, B_ * H_), 256, 0, stream>>>(keys, values, Kb, VtW);
    else
        prep_kv<false><<<dim3(S_ / 64, B_ * H_), 256, 0, stream>>>(keys, values, Kb, VtW);
    if (hasW) convw_kernel<<<(E_ * E_ / 8) / 256, 256, 0, stream>>>(w_out, Wb);

    // 1-D grid, XCD-aware decode inside the kernel (256 blocks)
    if (hasK)
        attn_mfma<true><<<dim3((S_ / QT) * H_ * B_), 512, 0, stream>>>(Kb, keys, queries, VtW, mask, Xb);
    else
        attn_mfma<false><<<dim3((S_ / QT) * H_ * B_), 512, 0, stream>>>(Kb, keys, queries, VtW, mask, Xb);

    // 1-D grid (512 blocks), XCD-aware decode inside the kernel
    if (hasW)
        proj_mfma<true><<<dim3(512), 512, 0, stream>>>(Xb, Wb, w_out, out);
    else
        proj_mfma<false><<<dim3(512), 512, 0, stream>>>(Xb, Wb, w_out, out);
}